// Round 5
// baseline (593.633 us; speedup 1.0000x reference)
//
#include <hip/hip_runtime.h>
#include <hip/hip_bf16.h>

#define ND 2048

using bf16 = __hip_bfloat16;
using short8 = __attribute__((ext_vector_type(8))) short;   // 8 bf16 = 4 VGPRs
using floatx4 = __attribute__((ext_vector_type(4))) float;

// ---------------- async global->LDS (16B per lane, wave-uniform LDS base) ----
__device__ __forceinline__ void gl2lds16(const short* g, short* l) {
    __builtin_amdgcn_global_load_lds(
        (const __attribute__((address_space(1))) unsigned int*)g,
        (__attribute__((address_space(3))) unsigned int*)l,
        16, 0, 0);
}

// chunked bijective XCD swizzle (requires grid % 8 == 0)
__device__ __forceinline__ int xcd_swz(int b, int g) {
    if ((g & 7) == 0) b = (b & 7) * (g >> 3) + (b >> 3);
    return b;
}

// ---------------- elementwise kernels ----------------

// Two skew builds in one dispatch: M = 0.5*(u^T - u), fp32 in -> bf16 out.
__global__ void build_skew2(const float* __restrict__ uA, bf16* __restrict__ MA,
                            const float* __restrict__ uB, bf16* __restrict__ MB) {
    __shared__ float t[32][33];
    const int nb = (ND / 32) * (ND / 32);
    int b = blockIdx.x;
    const float* u = uA;
    bf16* M = MA;
    if (b >= nb) { b -= nb; u = uB; M = MB; }
    const int bx = b & (ND / 32 - 1);
    const int by = b / (ND / 32);
    const int tx = threadIdx.x & 31;
    const int ty = threadIdx.x >> 5;   // 0..7
#pragma unroll
    for (int rr = 0; rr < 4; ++rr) {
        const int r = ty * 4 + rr;
        t[tx][r] = u[(size_t)(bx * 32 + r) * ND + by * 32 + tx];
    }
    __syncthreads();
#pragma unroll
    for (int rr = 0; rr < 4; ++rr) {
        const int r = ty * 4 + rr;
        const size_t idx = (size_t)(by * 32 + r) * ND + bx * 32 + tx;
        M[idx] = __float2bfloat16(0.5f * (t[r][tx] - u[idx]));
    }
}

// legacy merged hoff builder (old Tier-A fallback path)
__global__ void build_hoffs(const bf16* M2, const bf16* Q2, bf16* H2, bf16* HT2,
                            const bf16* M1, const bf16* Q1, bf16* H1) {
    const size_t nper = (size_t)ND * ND / 8;
    size_t g = (size_t)blockIdx.x * 256 + threadIdx.x;
    const bool second = (g >= nper);
    if (second) g -= nper;
    const size_t i8 = g * 8;
    const short8 mv = *(const short8*)((const short*)(second ? M1 : M2) + i8);
    const short8 qv = *(const short8*)((const short*)(second ? Q1 : Q2) + i8);
    short8 h, ht;
#pragma unroll
    for (int j = 0; j < 8; ++j) {
        const float m = __bfloat162float(__builtin_bit_cast(bf16, (short)mv[j]));
        const float q = __bfloat162float(__builtin_bit_cast(bf16, (short)qv[j]));
        h[j]  = __builtin_bit_cast(short, __float2bfloat16(2.f * m + q));
        ht[j] = __builtin_bit_cast(short, __float2bfloat16(q - 2.f * m));
    }
    if (second) {
        *(short8*)((short*)H1 + i8) = h;
    } else {
        *(short8*)((short*)H2 + i8) = h;
        *(short8*)((short*)HT2 + i8) = ht;
    }
}

// Tier-B variant
__global__ void build_hoff(const bf16* M, const bf16* Msq, bf16* Hoff, bf16* HoffT) {
    const size_t idx = (size_t)blockIdx.x * 256 + threadIdx.x;
    const float m = __bfloat162float(M[idx]);
    const float q = __bfloat162float(Msq[idx]);
    Hoff[idx] = __float2bfloat16(2.f * m + q);
    HoffT[idx] = __float2bfloat16(q - 2.f * m);
}

// x fp32 -> bf16, 8 elems/thread
__global__ void convert_f32_bf16(const float* __restrict__ x, bf16* __restrict__ y) {
    const size_t base = ((size_t)blockIdx.x * 256 + threadIdx.x) * 8;
    const float4 f0 = *(const float4*)(x + base);
    const float4 f1 = *(const float4*)(x + base + 4);
    short8 pk;
    pk[0] = __builtin_bit_cast(short, __float2bfloat16(f0.x));
    pk[1] = __builtin_bit_cast(short, __float2bfloat16(f0.y));
    pk[2] = __builtin_bit_cast(short, __float2bfloat16(f0.z));
    pk[3] = __builtin_bit_cast(short, __float2bfloat16(f0.w));
    pk[4] = __builtin_bit_cast(short, __float2bfloat16(f1.x));
    pk[5] = __builtin_bit_cast(short, __float2bfloat16(f1.y));
    pk[6] = __builtin_bit_cast(short, __float2bfloat16(f1.z));
    pk[7] = __builtin_bit_cast(short, __float2bfloat16(f1.w));
    *(short8*)((short*)y + base) = pk;
}

// ---------------- split-K reduce kernels (fp32 partials live in d_out) -------
__device__ __forceinline__ void loadS8(const float* p, float (&v)[8]) {
    const float4 a = *(const float4*)p;
    const float4 b = *(const float4*)(p + 4);
    v[0] = a.x; v[1] = a.y; v[2] = a.z; v[3] = a.w;
    v[4] = b.x; v[5] = b.y; v[6] = b.z; v[7] = b.w;
}
#define BF(x)   __bfloat162float(__builtin_bit_cast(bf16, (short)(x)))
#define TOBF(x) __builtin_bit_cast(short, __float2bfloat16(x))

// red1: Msq = -(s0+s1) [bf16], Hoff = 2M+Msq, HT2 = Msq2-2M2 (fused hoffs).
__global__ void red_msq_hoff(const float* __restrict__ S,
                             bf16* M2io /*b0: M2 in, HT2 out*/,
                             bf16* M1io /*b1: M1 in, Hoff1 out*/,
                             bf16* Msq2o /*b2*/, bf16* Msq1o /*b3*/,
                             bf16* Hoff2o /*b4*/) {
    const size_t MATE = (size_t)ND * ND;
    const size_t nper = MATE / 8;
    size_t g = (size_t)blockIdx.x * 256 + threadIdx.x;
    const bool c1 = (g >= nper);
    if (c1) g -= nper;
    const size_t i8 = g * 8;
    const float* s0 = S + (c1 ? 2 * MATE : 0) + i8;
    float p0[8], p1[8];
    loadS8(s0, p0); loadS8(s0 + MATE, p1);
    const short8 mv = *(const short8*)((const short*)(c1 ? M1io : M2io) + i8);
    short8 msq, hf, ht;
#pragma unroll
    for (int j = 0; j < 8; ++j) {
        const short qb = TOBF(-(p0[j] + p1[j]));
        msq[j] = qb;
        const float q = BF(qb);
        const float m = BF(mv[j]);
        hf[j] = TOBF(2.f * m + q);
        ht[j] = TOBF(q - 2.f * m);
    }
    if (c1) {
        *(short8*)((short*)Msq1o + i8) = msq;
        *(short8*)((short*)M1io + i8) = hf;
    } else {
        *(short8*)((short*)Msq2o + i8) = msq;
        *(short8*)((short*)Hoff2o + i8) = hf;
        *(short8*)((short*)M2io + i8) = ht;
    }
}

// red2: Goff = (s0+s1) + Msq  (in place over the Msq buffers)
__global__ void red_goff(const float* __restrict__ S, bf16* g2io /*b2*/, bf16* g1io /*b3*/) {
    const size_t MATE = (size_t)ND * ND;
    const size_t nper = MATE / 8;
    size_t g = (size_t)blockIdx.x * 256 + threadIdx.x;
    const bool c1 = (g >= nper);
    if (c1) g -= nper;
    const size_t i8 = g * 8;
    const float* s0 = S + (c1 ? 2 * MATE : 0) + i8;
    float p0[8], p1[8];
    loadS8(s0, p0); loadS8(s0 + MATE, p1);
    const short8 av = *(const short8*)((const short*)(c1 ? g1io : g2io) + i8);
    short8 o;
#pragma unroll
    for (int j = 0; j < 8; ++j)
        o[j] = TOBF((p0[j] + p1[j]) + BF(av[j]));
    *(short8*)((short*)(c1 ? g1io : g2io) + i8) = o;
}

// red3: P2T = s + I + Goff2 + HT2 -> b0 ; P1R = (s + I + Goff1 + Hoff1) @ R -> b1
__global__ void red_p(const float* __restrict__ S,
                      bf16* p2t /*b0: HT2 in, P2T out*/, const bf16* goff2 /*b2*/,
                      bf16* p1r /*b1: Hoff1 in, P1R out*/, const bf16* goff1 /*b3*/,
                      const float* __restrict__ thetaP) {
    const size_t MATE = (size_t)ND * ND;
    const size_t nper = MATE / 8;
    size_t g = (size_t)blockIdx.x * 256 + threadIdx.x;
    const bool c1 = (g >= nper);
    if (c1) g -= nper;
    const size_t i8 = g * 8;
    const float* s0 = S + (c1 ? 2 * MATE : 0) + i8;
    float p0[8], p1[8];
    loadS8(s0, p0); loadS8(s0 + MATE, p1);
    const short8 a1v = *(const short8*)((const short*)(c1 ? goff1 : goff2) + i8);
    const short8 a2v = *(const short8*)((const short*)(c1 ? p1r : p2t) + i8);
    float v[8];
#pragma unroll
    for (int j = 0; j < 8; ++j) {
        const size_t e = i8 + j;
        const float diag = ((e >> 11) == (e & (ND - 1))) ? 1.f : 0.f;
        v[j] = p0[j] + p1[j];
        v[j] += diag + BF(a1v[j]) + BF(a2v[j]);
    }
    short8 o;
    if (c1) {
        const float th = *thetaP;
        const float ct = cosf(th), st = sinf(th);
#pragma unroll
        for (int j = 0; j < 8; j += 2) {
            const float a = v[j], b = v[j + 1];
            o[j]     = TOBF(ct * a - st * b);
            o[j + 1] = TOBF(st * a + ct * b);
        }
        *(short8*)((short*)p1r + i8) = o;
    } else {
#pragma unroll
        for (int j = 0; j < 8; ++j) o[j] = TOBF(v[j]);
        *(short8*)((short*)p2t + i8) = o;
    }
}

// red4: QT = s0+s1+s2+s3 -> bf16
__global__ void red_qt(const float* __restrict__ S, bf16* __restrict__ q) {
    const size_t MATE = (size_t)ND * ND;
    const size_t i8 = ((size_t)blockIdx.x * 256 + threadIdx.x) * 8;
    float p0[8], p1[8], p2[8], p3[8];
    loadS8(S + i8, p0); loadS8(S + MATE + i8, p1);
    loadS8(S + 2 * MATE + i8, p2); loadS8(S + 3 * MATE + i8, p3);
    short8 o;
#pragma unroll
    for (int j = 0; j < 8; ++j)
        o[j] = TOBF(((p0[j] + p1[j]) + p2[j]) + p3[j]);
    *(short8*)((short*)q + i8) = o;
}

// ---------------- epilogue modes ----------------
enum { EPI_PLAIN = 0, EPI_NEG = 1, EPI_ADD1 = 2, EPI_P = 3, EPI_P_ROT = 4 };

// ---------------- 128x128 m97-structure GEMM core (fallback paths) -----------
template <int EPI, bool OF32>
__device__ __forceinline__ void gemm_core(
    short* aT, short* bT,
    const bf16* __restrict__ A, const bf16* __restrict__ Bt, void* __restrict__ Cp,
    const int Nc, const int K, const int bx, const int by,
    const bf16* __restrict__ add1, const bf16* __restrict__ add2,
    const float* __restrict__ thetaP)
{
    const int tid = threadIdx.x;
    const int lane = tid & 63;
    const int quad = lane >> 4;
    const int l15 = lane & 15;
    const int wv = tid >> 6;
    const int wr = (wv >> 1) << 6;
    const int wc = (wv & 1) << 6;

    const short* Ag = (const short*)A + (size_t)(by << 7) * K;
    const short* Bg = (const short*)Bt + (size_t)(bx << 7) * K;

    floatx4 acc[4][4];
#pragma unroll
    for (int i = 0; i < 4; ++i)
#pragma unroll
        for (int j = 0; j < 4; ++j)
            acc[i][j] = (floatx4){0.f, 0.f, 0.f, 0.f};

    for (int k0 = 0; k0 < K; k0 += 32) {
#pragma unroll
        for (int c = 0; c < 2; ++c) {
            const int ch = (c << 8) + (wv << 6) + lane;
            const int row = ch >> 2;
            const int kp = (ch & 3) << 3;
            const int ldsBase = ((c << 8) + (wv << 6)) << 3;
            gl2lds16(Ag + (size_t)row * K + k0 + kp, aT + ldsBase);
            gl2lds16(Bg + (size_t)row * K + k0 + kp, bT + ldsBase);
        }
        __syncthreads();
        short8 af[4], bfr[4];
#pragma unroll
        for (int mi = 0; mi < 4; ++mi)
            af[mi] = *(const short8*)(aT + ((wr + (mi << 4) + l15) << 5) + (quad << 3));
#pragma unroll
        for (int ni = 0; ni < 4; ++ni)
            bfr[ni] = *(const short8*)(bT + ((wc + (ni << 4) + l15) << 5) + (quad << 3));
#pragma unroll
        for (int mi = 0; mi < 4; ++mi)
#pragma unroll
            for (int ni = 0; ni < 4; ++ni)
                acc[mi][ni] = __builtin_amdgcn_mfma_f32_16x16x32_bf16(af[mi], bfr[ni], acc[mi][ni], 0, 0, 0);
        __syncthreads();
    }

    float ct = 0.f, st = 0.f;
    if (EPI == EPI_P_ROT) {
        const float th = *thetaP;
        ct = cosf(th);
        st = sinf(th);
    }

#pragma unroll
    for (int mi = 0; mi < 4; ++mi) {
#pragma unroll
        for (int ni = 0; ni < 4; ++ni) {
#pragma unroll
            for (int r = 0; r < 4; ++r) {
                const int row = (by << 7) + wr + (mi << 4) + (quad << 2) + r;
                const int col = (bx << 7) + wc + (ni << 4) + l15;
                const size_t idx = (size_t)row * Nc + col;
                float v = acc[mi][ni][r];
                if (EPI == EPI_NEG) v = -v;
                if (EPI == EPI_ADD1) v += __bfloat162float(add1[idx]);
                if (EPI == EPI_P)
                    v += (row == col ? 1.f : 0.f)
                       + __bfloat162float(add1[idx]) + __bfloat162float(add2[idx]);
                if (EPI == EPI_P_ROT) {
                    v += (row == col ? 1.f : 0.f)
                       + __bfloat162float(add1[idx]) + __bfloat162float(add2[idx]);
                    const float w = __shfl_xor(v, 1, 64);
                    v = (l15 & 1) ? (st * w + ct * v) : (ct * v - st * w);
                }
                if (OF32) ((float*)Cp)[idx] = v;
                else      ((bf16*)Cp)[idx] = __float2bfloat16(v);
            }
        }
    }
}

template <int EPI, bool OF32>
__launch_bounds__(256, 2) __global__
void gemm_one(const bf16* __restrict__ A, const bf16* __restrict__ Bt,
              void* __restrict__ Cp, const int Nc, const int K,
              const bf16* __restrict__ add1, const bf16* __restrict__ add2,
              const float* __restrict__ thetaP)
{
    __shared__ __attribute__((aligned(16))) short aT[128 * 32];
    __shared__ __attribute__((aligned(16))) short bT[128 * 32];
    const int nblk = Nc >> 7;
    const int b = xcd_swz(blockIdx.x, gridDim.x);
    gemm_core<EPI, OF32>(aT, bT, A, Bt, Cp, Nc, K, b % nblk, b / nblk,
                         add1, add2, thetaP);
}

template <int EPI0, int EPI1>
__launch_bounds__(256, 2) __global__
void gemm_dual(const bf16* A0, const bf16* B0, bf16* C0, const bf16* a10, const bf16* a20,
               const bf16* A1, const bf16* B1, bf16* C1, const bf16* a11, const bf16* a21,
               const float* thetaP)
{
    __shared__ __attribute__((aligned(16))) short aT[128 * 32];
    __shared__ __attribute__((aligned(16))) short bT[128 * 32];
    const int nblk = ND >> 7;          // 16
    const int nsub = nblk * nblk;      // 256
    int b = xcd_swz(blockIdx.x, gridDim.x);
    if (b < nsub) {
        gemm_core<EPI0, false>(aT, bT, A0, B0, (void*)C0, ND, ND, b % nblk, b / nblk, a10, a20, thetaP);
    } else {
        b -= nsub;
        gemm_core<EPI1, false>(aT, bT, A1, B1, (void*)C1, ND, ND, b % nblk, b / nblk, a11, a21, thetaP);
    }
}

// ================== 256x256 / BK=64 / 8-phase / counted-vmcnt core ===========
// (R3-proven schedule; generalized with kOff for split-K use.)

__device__ __forceinline__ void stage512(short* ldsT, const short* gT, const int K,
                                         const int kb, const int c0,
                                         const int wv, const int lane) {
    const int ch = c0 + (wv << 6) + lane;      // chunk index in 256x64 tile
    const int rw = ch >> 3;                    // row (8 chunks of 16B per row)
    const int cs = (ch & 7) ^ (rw & 7);        // inverse-swizzled source k-chunk
    gl2lds16(gT + (size_t)rw * K + kb + (cs << 3),
             ldsT + ((c0 + (wv << 6)) << 3));  // wave-uniform linear LDS dest
}

__device__ __forceinline__ void phase_mid() {
    __builtin_amdgcn_sched_barrier(0);
    __builtin_amdgcn_s_barrier();
    asm volatile("s_waitcnt lgkmcnt(0)" ::: "memory");
    __builtin_amdgcn_sched_barrier(0);
    __builtin_amdgcn_s_setprio(1);
}
__device__ __forceinline__ void phase_end() {
    __builtin_amdgcn_s_setprio(0);
    __builtin_amdgcn_sched_barrier(0);
    __builtin_amdgcn_s_barrier();
}

#define MFMA_BF16 __builtin_amdgcn_mfma_f32_16x16x32_bf16

__device__ __forceinline__ void tile256(
    short* Ac, short* Bc, short* An,
    const short* Ag, const short* Bg, const int K, const int nt, const int t,
    const int kOff,
    const int wv, const int lane, const int aBase, const int bBase,
    const int cOff0, const int cOff1, floatx4 (&acc)[8][4])
{
    short8 af[4][2], bb[4][2];
    const int kb1 = kOff + ((t + 1) << 6);
    const int kb2 = kOff + ((t + 2) << 6);

    // ---- phase 1: ds_read A rows mi0-3 + B ni0-1 (12 reads); stage (t+1) A2 -> An
#pragma unroll
    for (int ml = 0; ml < 4; ++ml) {
        af[ml][0] = *(const short8*)(Ac + aBase + (ml << 10) + cOff0);
        af[ml][1] = *(const short8*)(Ac + aBase + (ml << 10) + cOff1);
    }
#pragma unroll
    for (int ni = 0; ni < 2; ++ni) {
        bb[ni][0] = *(const short8*)(Bc + bBase + (ni << 10) + cOff0);
        bb[ni][1] = *(const short8*)(Bc + bBase + (ni << 10) + cOff1);
    }
    if (t + 1 < nt) { stage512(An, Ag, K, kb1, 512, wv, lane); stage512(An, Ag, K, kb1, 1536, wv, lane); }
    __builtin_amdgcn_sched_barrier(0);
    asm volatile("s_waitcnt lgkmcnt(8)" ::: "memory");
    phase_mid();
#pragma unroll
    for (int ml = 0; ml < 4; ++ml)
#pragma unroll
        for (int ni = 0; ni < 2; ++ni) {
            acc[ml][ni] = MFMA_BF16(af[ml][0], bb[ni][0], acc[ml][ni], 0, 0, 0);
            acc[ml][ni] = MFMA_BF16(af[ml][1], bb[ni][1], acc[ml][ni], 0, 0, 0);
        }
    phase_end();

    // ---- phase 2: ds_read B ni2-3 ; stage (t+2) A1 -> Ac
#pragma unroll
    for (int ni = 2; ni < 4; ++ni) {
        bb[ni][0] = *(const short8*)(Bc + bBase + (ni << 10) + cOff0);
        bb[ni][1] = *(const short8*)(Bc + bBase + (ni << 10) + cOff1);
    }
    if (t + 2 < nt) { stage512(Ac, Ag, K, kb2, 0, wv, lane); stage512(Ac, Ag, K, kb2, 1024, wv, lane); }
    phase_mid();
#pragma unroll
    for (int ml = 0; ml < 4; ++ml)
#pragma unroll
        for (int ni = 2; ni < 4; ++ni) {
            acc[ml][ni] = MFMA_BF16(af[ml][0], bb[ni][0], acc[ml][ni], 0, 0, 0);
            acc[ml][ni] = MFMA_BF16(af[ml][1], bb[ni][1], acc[ml][ni], 0, 0, 0);
        }
    phase_end();

    // ---- phase 3: ds_read A rows mi4-7 ; stage (t+2) B rows 0-127
#pragma unroll
    for (int ml = 0; ml < 4; ++ml) {
        af[ml][0] = *(const short8*)(Ac + aBase + 4096 + (ml << 10) + cOff0);
        af[ml][1] = *(const short8*)(Ac + aBase + 4096 + (ml << 10) + cOff1);
    }
    if (t + 2 < nt) { stage512(Bc, Bg, K, kb2, 0, wv, lane); stage512(Bc, Bg, K, kb2, 512, wv, lane); }
    phase_mid();
#pragma unroll
    for (int ml = 0; ml < 4; ++ml)
#pragma unroll
        for (int ni = 0; ni < 2; ++ni) {
            acc[4 + ml][ni] = MFMA_BF16(af[ml][0], bb[ni][0], acc[4 + ml][ni], 0, 0, 0);
            acc[4 + ml][ni] = MFMA_BF16(af[ml][1], bb[ni][1], acc[4 + ml][ni], 0, 0, 0);
        }
    phase_end();

    // ---- phase 4: stage (t+2) B rows 128-255 ; counted vmcnt for tile t+1
    if (t + 2 < nt) { stage512(Bc, Bg, K, kb2, 1024, wv, lane); stage512(Bc, Bg, K, kb2, 1536, wv, lane); }
    __builtin_amdgcn_sched_barrier(0);
    if (t < nt - 2) asm volatile("s_waitcnt vmcnt(6)" ::: "memory");
    else            asm volatile("s_waitcnt vmcnt(0)" ::: "memory");
    __builtin_amdgcn_s_barrier();
    __builtin_amdgcn_sched_barrier(0);
    __builtin_amdgcn_s_setprio(1);
#pragma unroll
    for (int ml = 0; ml < 4; ++ml)
#pragma unroll
        for (int ni = 2; ni < 4; ++ni) {
            acc[4 + ml][ni] = MFMA_BF16(af[ml][0], bb[ni][0], acc[4 + ml][ni], 0, 0, 0);
            acc[4 + ml][ni] = MFMA_BF16(af[ml][1], bb[ni][1], acc[4 + ml][ni], 0, 0, 0);
        }
    phase_end();
}

__launch_bounds__(512, 2) __global__
void gemm_big256(const bf16* __restrict__ A, const bf16* __restrict__ Bt,
                 float* __restrict__ C, const int Nc, const int K)
{
    __shared__ __attribute__((aligned(16))) short smem[65536];   // 128 KiB
    short* A0s = smem;
    short* A1s = smem + 16384;
    short* B0s = smem + 32768;
    short* B1s = smem + 49152;

    const int nblkx = Nc >> 8;                 // 8
    const int b = xcd_swz(blockIdx.x, gridDim.x);
    const int bx = b % nblkx;
    const int by = b / nblkx;
    const int tid = threadIdx.x;
    const int lane = tid & 63;
    const int q = lane >> 4;
    const int l15 = lane & 15;
    const int wv = tid >> 6;
    const int wm = wv >> 2;
    const int wn = wv & 3;

    const short* Ag = (const short*)A + (size_t)(by << 8) * K;
    const short* Bg = (const short*)Bt + (size_t)(bx << 8) * K;

    const int swz = l15 & 7;
    const int aBase = ((wm << 7) + l15) << 6;
    const int bBase = ((wn << 6) + l15) << 6;
    const int cOff0 = (q ^ swz) << 3;
    const int cOff1 = ((q + 4) ^ swz) << 3;

    floatx4 acc[8][4];
#pragma unroll
    for (int i = 0; i < 8; ++i)
#pragma unroll
        for (int j = 0; j < 4; ++j)
            acc[i][j] = (floatx4){0.f, 0.f, 0.f, 0.f};

    const int nt = K >> 6;

    stage512(A0s, Ag, K, 0, 0,    wv, lane);
    stage512(A0s, Ag, K, 0, 512,  wv, lane);
    stage512(A0s, Ag, K, 0, 1024, wv, lane);
    stage512(A0s, Ag, K, 0, 1536, wv, lane);
    stage512(B0s, Bg, K, 0, 0,    wv, lane);
    stage512(B0s, Bg, K, 0, 512,  wv, lane);
    stage512(B0s, Bg, K, 0, 1024, wv, lane);
    stage512(B0s, Bg, K, 0, 1536, wv, lane);
    stage512(A1s, Ag, K, 64, 0,    wv, lane);
    stage512(A1s, Ag, K, 64, 1024, wv, lane);
    stage512(B1s, Bg, K, 64, 0,    wv, lane);
    stage512(B1s, Bg, K, 64, 512,  wv, lane);
    stage512(B1s, Bg, K, 64, 1024, wv, lane);
    stage512(B1s, Bg, K, 64, 1536, wv, lane);
    __builtin_amdgcn_sched_barrier(0);
    asm volatile("s_waitcnt vmcnt(6)" ::: "memory");
    __builtin_amdgcn_s_barrier();

    for (int t = 0; t < nt; t += 2) {
        tile256(A0s, B0s, A1s, Ag, Bg, K, nt, t,     0, wv, lane, aBase, bBase, cOff0, cOff1, acc);
        tile256(A1s, B1s, A0s, Ag, Bg, K, nt, t + 1, 0, wv, lane, aBase, bBase, cOff0, cOff1, acc);
    }

#pragma unroll
    for (int mi = 0; mi < 8; ++mi)
#pragma unroll
        for (int ni = 0; ni < 4; ++ni)
#pragma unroll
            for (int r = 0; r < 4; ++r) {
                const int row = (by << 8) + (wm << 7) + (mi << 4) + (q << 2) + r;
                const int col = (bx << 8) + (wn << 6) + (ni << 4) + l15;
                C[(size_t)row * Nc + col] = acc[mi][ni][r];
            }
}

// ---------------- split-K chain GEMM: 256 blocks, fp32 partials to S ---------
// NT=16: 2 GEMMs x 2 K-splits (K=1024 each).  NT=8: 1 GEMM x 4 K-splits (512).
// Output sub i -> S + i*ND*ND (row-major fp32 2048^2 partial).
template <int NT>
__launch_bounds__(512, 2) __global__
void gemm_sk(const bf16* __restrict__ A0, const bf16* __restrict__ B0,
             const bf16* __restrict__ A1, const bf16* __restrict__ B1,
             float* __restrict__ S)
{
    __shared__ __attribute__((aligned(16))) short smem[65536];   // 128 KiB
    short* A0s = smem;
    short* A1s = smem + 16384;
    short* B0s = smem + 32768;
    short* B1s = smem + 49152;

    const int b = xcd_swz(blockIdx.x, gridDim.x);   // grid = 256
    const int sub = b >> 6;
    const int t6 = b & 63;
    const int bx = t6 & 7;
    const int by = t6 >> 3;
    const bf16* A; const bf16* Bt; int kOff;
    if (NT == 16) { A = (sub & 2) ? A1 : A0; Bt = (sub & 2) ? B1 : B0; kOff = (sub & 1) << 10; }
    else          { A = A0; Bt = B0; kOff = sub << 9; }
    float* C = S + (size_t)sub * ((size_t)ND * ND);
    const int K = ND;

    const int tid = threadIdx.x;
    const int lane = tid & 63;
    const int q = lane >> 4;
    const int l15 = lane & 15;
    const int wv = tid >> 6;
    const int wm = wv >> 2;
    const int wn = wv & 3;

    const short* Ag = (const short*)A + (size_t)(by << 8) * K;
    const short* Bg = (const short*)Bt + (size_t)(bx << 8) * K;

    const int swz = l15 & 7;
    const int aBase = ((wm << 7) + l15) << 6;
    const int bBase = ((wn << 6) + l15) << 6;
    const int cOff0 = (q ^ swz) << 3;
    const int cOff1 = ((q + 4) ^ swz) << 3;

    floatx4 acc[8][4];
#pragma unroll
    for (int i = 0; i < 8; ++i)
#pragma unroll
        for (int j = 0; j < 4; ++j)
            acc[i][j] = (floatx4){0.f, 0.f, 0.f, 0.f};

    // prologue: T0 full + T1 {A-part1, B-full}; wait T0.
    stage512(A0s, Ag, K, kOff, 0,    wv, lane);
    stage512(A0s, Ag, K, kOff, 512,  wv, lane);
    stage512(A0s, Ag, K, kOff, 1024, wv, lane);
    stage512(A0s, Ag, K, kOff, 1536, wv, lane);
    stage512(B0s, Bg, K, kOff, 0,    wv, lane);
    stage512(B0s, Bg, K, kOff, 512,  wv, lane);
    stage512(B0s, Bg, K, kOff, 1024, wv, lane);
    stage512(B0s, Bg, K, kOff, 1536, wv, lane);
    stage512(A1s, Ag, K, kOff + 64, 0,    wv, lane);
    stage512(A1s, Ag, K, kOff + 64, 1024, wv, lane);
    stage512(B1s, Bg, K, kOff + 64, 0,    wv, lane);
    stage512(B1s, Bg, K, kOff + 64, 512,  wv, lane);
    stage512(B1s, Bg, K, kOff + 64, 1024, wv, lane);
    stage512(B1s, Bg, K, kOff + 64, 1536, wv, lane);
    __builtin_amdgcn_sched_barrier(0);
    asm volatile("s_waitcnt vmcnt(6)" ::: "memory");
    __builtin_amdgcn_s_barrier();

    for (int t = 0; t < NT; t += 2) {
        tile256(A0s, B0s, A1s, Ag, Bg, K, NT, t,     kOff, wv, lane, aBase, bBase, cOff0, cOff1, acc);
        tile256(A1s, B1s, A0s, Ag, Bg, K, NT, t + 1, kOff, wv, lane, aBase, bBase, cOff0, cOff1, acc);
    }

#pragma unroll
    for (int mi = 0; mi < 8; ++mi)
#pragma unroll
        for (int ni = 0; ni < 4; ++ni)
#pragma unroll
            for (int r = 0; r < 4; ++r) {
                const int row = (by << 8) + (wm << 7) + (mi << 4) + (q << 2) + r;
                const int col = (bx << 8) + (wn << 6) + (ni << 4) + l15;
                C[(size_t)row * ND + col] = acc[mi][ni][r];
            }
}

// ---------------- Tier-B (round-2 proven) manual-staging GEMM ----------------
template <int EPI, bool AF32, bool OF32>
__launch_bounds__(256, 2) __global__
void gemm_bt(const void* __restrict__ Ap, const bf16* __restrict__ Bt,
             void* __restrict__ Cp, const int Nc, const int K,
             const bf16* __restrict__ add1, const bf16* __restrict__ add2,
             const float* __restrict__ thetaP)
{
    __shared__ __attribute__((aligned(16))) short aT[128 * 32];
    __shared__ __attribute__((aligned(16))) short bT[128 * 32];

    const int nblk = Nc >> 7;
    const int bx = blockIdx.x % nblk;
    const int by = blockIdx.x / nblk;
    const int tid = threadIdx.x;
    const int lane = tid & 63;
    const int quad = lane >> 4;
    const int l15 = lane & 15;
    const int wv = tid >> 6;
    const int wr = (wv >> 1) << 6;
    const int wc = (wv & 1) << 6;

    const short* Ag = (const short*)Ap + (size_t)(by << 7) * K;
    const float* Agf = (const float*)Ap + (size_t)(by << 7) * K;
    const short* Bg = (const short*)Bt + (size_t)(bx << 7) * K;

    floatx4 acc[4][4];
#pragma unroll
    for (int i = 0; i < 4; ++i)
#pragma unroll
        for (int j = 0; j < 4; ++j)
            acc[i][j] = (floatx4){0.f, 0.f, 0.f, 0.f};

    for (int k0 = 0; k0 < K; k0 += 32) {
#pragma unroll
        for (int c = 0; c < 2; ++c) {
            const int ch = tid + (c << 8);
            const int row = ch >> 2;
            const int kp = (ch & 3) << 3;
            if (AF32) {
                const float4 f0 = *(const float4*)(Agf + (size_t)row * K + k0 + kp);
                const float4 f1 = *(const float4*)(Agf + (size_t)row * K + k0 + kp + 4);
                short8 pk;
                pk[0] = __builtin_bit_cast(short, __float2bfloat16(f0.x));
                pk[1] = __builtin_bit_cast(short, __float2bfloat16(f0.y));
                pk[2] = __builtin_bit_cast(short, __float2bfloat16(f0.z));
                pk[3] = __builtin_bit_cast(short, __float2bfloat16(f0.w));
                pk[4] = __builtin_bit_cast(short, __float2bfloat16(f1.x));
                pk[5] = __builtin_bit_cast(short, __float2bfloat16(f1.y));
                pk[6] = __builtin_bit_cast(short, __float2bfloat16(f1.z));
                pk[7] = __builtin_bit_cast(short, __float2bfloat16(f1.w));
                *(short8*)(aT + (row << 5) + kp) = pk;
            } else {
                *(int4*)(aT + (row << 5) + kp) = *(const int4*)(Ag + (size_t)row * K + k0 + kp);
            }
            *(int4*)(bT + (row << 5) + kp) = *(const int4*)(Bg + (size_t)row * K + k0 + kp);
        }
        __syncthreads();
        short8 af[4], bfr[4];
#pragma unroll
        for (int mi = 0; mi < 4; ++mi)
            af[mi] = *(const short8*)(aT + ((wr + (mi << 4) + l15) << 5) + (quad << 3));
#pragma unroll
        for (int ni = 0; ni < 4; ++ni)
            bfr[ni] = *(const short8*)(bT + ((wc + (ni << 4) + l15) << 5) + (quad << 3));
#pragma unroll
        for (int mi = 0; mi < 4; ++mi)
#pragma unroll
            for (int ni = 0; ni < 4; ++ni)
                acc[mi][ni] = __builtin_amdgcn_mfma_f32_16x16x32_bf16(af[mi], bfr[ni], acc[mi][ni], 0, 0, 0);
        __syncthreads();
    }

    float ct = 0.f, st = 0.f;
    if (EPI == EPI_P_ROT) {
        const float th = *thetaP;
        ct = cosf(th);
        st = sinf(th);
    }

#pragma unroll
    for (int mi = 0; mi < 4; ++mi) {
#pragma unroll
        for (int ni = 0; ni < 4; ++ni) {
#pragma unroll
            for (int r = 0; r < 4; ++r) {
                const int row = (by << 7) + wr + (mi << 4) + (quad << 2) + r;
                const int col = (bx << 7) + wc + (ni << 4) + l15;
                const size_t idx = (size_t)row * Nc + col;
                float v = acc[mi][ni][r];
                if (EPI == EPI_NEG) v = -v;
                if (EPI == EPI_ADD1) v += __bfloat162float(add1[idx]);
                if (EPI == EPI_P || EPI == EPI_P_ROT)
                    v += (row == col ? 1.f : 0.f)
                       + __bfloat162float(add1[idx]) + __bfloat162float(add2[idx]);
                if (EPI == EPI_P_ROT) {
                    const float w = __shfl_xor(v, 1, 64);
                    v = (l15 & 1) ? (st * w + ct * v) : (ct * v - st * w);
                }
                if (OF32) ((float*)Cp)[idx] = v;
                else      ((bf16*)Cp)[idx] = __float2bfloat16(v);
            }
        }
    }
}

// ---------------- launch ----------------
// out = x @ P1 @ R @ P2,  P = (I+M)^2 (I+M^2+M^4),  M = 0.5(W^T - W)
// Tier A+ (tokens%256==0 and out holds 8 fp32 2048^2 partials): entire chain on
//   the 256^2 8-phase kernel via split-K, fp32 partials in d_out, vectorized
//   deterministic reduces carrying all epilogue algebra.  Full-machine grids.
// Tier A fallback: R4 dual-chain.  Tier B: round-2 proven sequence.

extern "C" void kernel_launch(void* const* d_in, const int* in_sizes, int n_in,
                              void* d_out, int out_size, void* d_ws, size_t ws_size,
                              hipStream_t stream)
{
    const float* x = (const float*)d_in[0];
    const float* u1 = (const float*)d_in[1];
    const float* u2 = (const float*)d_in[2];
    const float* th = (const float*)d_in[3];
    float* out = (float*)d_out;
    const int tokens = in_sizes[0] / ND;

    const size_t MAT = (size_t)ND * ND;
    const size_t XBE = (size_t)tokens * ND;

    const dim3 blk(256);
    const int gSkew = (ND / 32) * (ND / 32);
    const int gElem = (int)(MAT / 256);
    const int gSm = (ND / 128) * (ND / 128);        // 256
    const int gBig = (tokens / 128) * (ND / 128);

    if (ws_size >= (6 * MAT + XBE) * sizeof(bf16)) {
        bf16* base = (bf16*)d_ws;
        bf16* b0 = base;            // M2 -> HT2 -> P2T
        bf16* b1 = base + MAT;      // M1 -> Hoff1 -> P1R
        bf16* b2 = base + 2 * MAT;  // Msq2 -> Goff2 -> QT
        bf16* b3 = base + 3 * MAT;  // Msq1 -> Goff1
        bf16* b4 = base + 4 * MAT;  // Hoff2
        bf16* xb = base + 6 * MAT;  // x as bf16

        convert_f32_bf16<<<(int)(XBE / 2048), blk, 0, stream>>>(x, xb);
        build_skew2<<<2 * gSkew, blk, 0, stream>>>(u2, b0, u1, b1);

        if ((tokens & 255) == 0 && (size_t)out_size >= 8 * MAT * sizeof(float)) {
            // ---------------- Tier A+: split-K chain, partials in d_out ------
            float* S = out;
            const int gRed = (int)(2 * MAT / 2048);
            // stage1: Msq partials  (g0 = M2@M2^T, g1 = M1@M1^T)
            gemm_sk<16><<<256, dim3(512), 0, stream>>>(b0, b0, b1, b1, S);
            // Msq = -(s0+s1); Hoff = 2M+Msq; HT2 = Msq2-2M2 (fused)
            red_msq_hoff<<<gRed, blk, 0, stream>>>(S, b0, b1, b2, b3, b4);
            // stage2: Goff partials (g0 = Msq2@Msq2, g1 = Msq1@Msq1)
            gemm_sk<16><<<256, dim3(512), 0, stream>>>(b2, b2, b3, b3, S);
            // Goff = (s0+s1) + Msq  (in place over Msq)
            red_goff<<<gRed, blk, 0, stream>>>(S, b2, b3);
            // stage3: P partials (g0 = Goff2@Hoff2^T, g1 = Hoff1@Goff1^T)
            gemm_sk<16><<<256, dim3(512), 0, stream>>>(b2, b4, b1, b3, S);
            // P2T = s+I+Goff2+HT2 -> b0 ; P1R = (s+I+Goff1+Hoff1)@R -> b1
            red_p<<<gRed, blk, 0, stream>>>(S, b0, b2, b1, b3, th);
            // QT partials: P2T @ P1R^T, split-K=4
            gemm_sk<8><<<256, dim3(512), 0, stream>>>(b0, b1, nullptr, nullptr, S);
            red_qt<<<(int)(MAT / 2048), blk, 0, stream>>>(S, b2);
            // out = x @ QT^T
            const int gBig256 = (tokens >> 8) * (ND >> 8);   // 512
            gemm_big256<<<gBig256, dim3(512), 0, stream>>>(xb, b2, out, ND, ND);
        } else {
            // ---------------- Tier A fallback (R4 path) ----------------------
            bf16* b5 = base + 5 * MAT;
            gemm_dual<EPI_NEG, EPI_NEG><<<2 * gSm, blk, 0, stream>>>(
                b0, b0, b2, nullptr, nullptr,  b1, b1, b3, nullptr, nullptr, nullptr);
            gemm_dual<EPI_ADD1, EPI_ADD1><<<2 * gSm, blk, 0, stream>>>(
                b2, b2, b4, b2, nullptr,  b3, b3, b5, b3, nullptr, nullptr);
            build_hoffs<<<(int)(2 * MAT / 2048), blk, 0, stream>>>(b0, b2, b2, b0, b1, b3, b3);
            gemm_dual<EPI_P, EPI_P_ROT><<<2 * gSm, blk, 0, stream>>>(
                b4, b2, b0, b4, b0,  b3, b5, b1, b5, b3, th);
            gemm_one<EPI_PLAIN, false><<<gSm, blk, 0, stream>>>(b0, b1, b2, ND, ND, nullptr, nullptr, nullptr);
            gemm_one<EPI_PLAIN, true><<<gBig, blk, 0, stream>>>(xb, b2, out, ND, ND, nullptr, nullptr, nullptr);
        }
    } else {
        // ---------------- Tier B (round-2 proven) ----------------
        bf16* A = (bf16*)d_ws;
        bf16* B = A + MAT;
        bf16* Cb = B + MAT;
        bf16* D = Cb + MAT;
        bf16* E = D + MAT;

        build_skew2<<<gSkew, blk, 0, stream>>>(u2, A, u2, A);
        gemm_bt<EPI_NEG, false, false><<<gSm, blk, 0, stream>>>(A, A, B, ND, ND, nullptr, nullptr, nullptr);
        gemm_bt<EPI_ADD1, false, false><<<gSm, blk, 0, stream>>>(B, B, Cb, ND, ND, B, nullptr, nullptr);
        build_hoff<<<gElem, blk, 0, stream>>>(A, B, D, E);
        gemm_bt<EPI_P, false, false><<<gSm, blk, 0, stream>>>(Cb, D, A, ND, ND, Cb, E, nullptr);

        build_skew2<<<gSkew, blk, 0, stream>>>(u1, B, u1, B);
        gemm_bt<EPI_NEG, false, false><<<gSm, blk, 0, stream>>>(B, B, Cb, ND, ND, nullptr, nullptr, nullptr);
        gemm_bt<EPI_ADD1, false, false><<<gSm, blk, 0, stream>>>(Cb, Cb, D, ND, ND, Cb, nullptr, nullptr);
        build_hoff<<<gElem, blk, 0, stream>>>(B, Cb, E, B);
        gemm_bt<EPI_P_ROT, false, false><<<gSm, blk, 0, stream>>>(E, D, Cb, ND, ND, D, E, th);

        gemm_bt<EPI_PLAIN, false, false><<<gSm, blk, 0, stream>>>(A, Cb, D, ND, ND, nullptr, nullptr, nullptr);
        gemm_bt<EPI_PLAIN, true, true><<<gBig, blk, 0, stream>>>(x, D, out, ND, ND, nullptr, nullptr, nullptr);
    }
}

// Round 6
// 572.820 us; speedup vs baseline: 1.0363x; 1.0363x over previous
//
#include <hip/hip_runtime.h>
#include <hip/hip_bf16.h>

#define ND 2048

using bf16 = __hip_bfloat16;
using short8 = __attribute__((ext_vector_type(8))) short;   // 8 bf16 = 4 VGPRs
using floatx4 = __attribute__((ext_vector_type(4))) float;

// ---------------- async global->LDS (16B per lane, wave-uniform LDS base) ----
__device__ __forceinline__ void gl2lds16(const short* g, short* l) {
    __builtin_amdgcn_global_load_lds(
        (const __attribute__((address_space(1))) unsigned int*)g,
        (__attribute__((address_space(3))) unsigned int*)l,
        16, 0, 0);
}

// chunked bijective XCD swizzle (requires grid % 8 == 0)
__device__ __forceinline__ int xcd_swz(int b, int g) {
    if ((g & 7) == 0) b = (b & 7) * (g >> 3) + (b >> 3);
    return b;
}

// ---------------- elementwise kernels ----------------

// Two skew builds in one dispatch: M = 0.5*(u^T - u), fp32 in -> bf16 out.
__global__ void build_skew2(const float* __restrict__ uA, bf16* __restrict__ MA,
                            const float* __restrict__ uB, bf16* __restrict__ MB) {
    __shared__ float t[32][33];
    const int nb = (ND / 32) * (ND / 32);
    int b = blockIdx.x;
    const float* u = uA;
    bf16* M = MA;
    if (b >= nb) { b -= nb; u = uB; M = MB; }
    const int bx = b & (ND / 32 - 1);
    const int by = b / (ND / 32);
    const int tx = threadIdx.x & 31;
    const int ty = threadIdx.x >> 5;   // 0..7
#pragma unroll
    for (int rr = 0; rr < 4; ++rr) {
        const int r = ty * 4 + rr;
        t[tx][r] = u[(size_t)(bx * 32 + r) * ND + by * 32 + tx];
    }
    __syncthreads();
#pragma unroll
    for (int rr = 0; rr < 4; ++rr) {
        const int r = ty * 4 + rr;
        const size_t idx = (size_t)(by * 32 + r) * ND + bx * 32 + tx;
        M[idx] = __float2bfloat16(0.5f * (t[r][tx] - u[idx]));
    }
}

// legacy merged hoff builder (old Tier-A fallback path)
__global__ void build_hoffs(const bf16* M2, const bf16* Q2, bf16* H2, bf16* HT2,
                            const bf16* M1, const bf16* Q1, bf16* H1) {
    const size_t nper = (size_t)ND * ND / 8;
    size_t g = (size_t)blockIdx.x * 256 + threadIdx.x;
    const bool second = (g >= nper);
    if (second) g -= nper;
    const size_t i8 = g * 8;
    const short8 mv = *(const short8*)((const short*)(second ? M1 : M2) + i8);
    const short8 qv = *(const short8*)((const short*)(second ? Q1 : Q2) + i8);
    short8 h, ht;
#pragma unroll
    for (int j = 0; j < 8; ++j) {
        const float m = __bfloat162float(__builtin_bit_cast(bf16, (short)mv[j]));
        const float q = __bfloat162float(__builtin_bit_cast(bf16, (short)qv[j]));
        h[j]  = __builtin_bit_cast(short, __float2bfloat16(2.f * m + q));
        ht[j] = __builtin_bit_cast(short, __float2bfloat16(q - 2.f * m));
    }
    if (second) {
        *(short8*)((short*)H1 + i8) = h;
    } else {
        *(short8*)((short*)H2 + i8) = h;
        *(short8*)((short*)HT2 + i8) = ht;
    }
}

// Tier-B variant
__global__ void build_hoff(const bf16* M, const bf16* Msq, bf16* Hoff, bf16* HoffT) {
    const size_t idx = (size_t)blockIdx.x * 256 + threadIdx.x;
    const float m = __bfloat162float(M[idx]);
    const float q = __bfloat162float(Msq[idx]);
    Hoff[idx] = __float2bfloat16(2.f * m + q);
    HoffT[idx] = __float2bfloat16(q - 2.f * m);
}

// x fp32 -> bf16, 8 elems/thread
__global__ void convert_f32_bf16(const float* __restrict__ x, bf16* __restrict__ y) {
    const size_t base = ((size_t)blockIdx.x * 256 + threadIdx.x) * 8;
    const float4 f0 = *(const float4*)(x + base);
    const float4 f1 = *(const float4*)(x + base + 4);
    short8 pk;
    pk[0] = __builtin_bit_cast(short, __float2bfloat16(f0.x));
    pk[1] = __builtin_bit_cast(short, __float2bfloat16(f0.y));
    pk[2] = __builtin_bit_cast(short, __float2bfloat16(f0.z));
    pk[3] = __builtin_bit_cast(short, __float2bfloat16(f0.w));
    pk[4] = __builtin_bit_cast(short, __float2bfloat16(f1.x));
    pk[5] = __builtin_bit_cast(short, __float2bfloat16(f1.y));
    pk[6] = __builtin_bit_cast(short, __float2bfloat16(f1.z));
    pk[7] = __builtin_bit_cast(short, __float2bfloat16(f1.w));
    *(short8*)((short*)y + base) = pk;
}

// ---------------- split-K reduce kernels (fp32 partials live in d_out) -------
__device__ __forceinline__ void loadS8(const float* p, float (&v)[8]) {
    const float4 a = *(const float4*)p;
    const float4 b = *(const float4*)(p + 4);
    v[0] = a.x; v[1] = a.y; v[2] = a.z; v[3] = a.w;
    v[4] = b.x; v[5] = b.y; v[6] = b.z; v[7] = b.w;
}
#define BF(x)   __bfloat162float(__builtin_bit_cast(bf16, (short)(x)))
#define TOBF(x) __builtin_bit_cast(short, __float2bfloat16(x))

// red1: Msq = -(s0+s1) [bf16], Hoff = 2M+Msq, HT2 = Msq2-2M2 (fused hoffs).
__global__ void red_msq_hoff(const float* __restrict__ S,
                             bf16* M2io /*b0: M2 in, HT2 out*/,
                             bf16* M1io /*b1: M1 in, Hoff1 out*/,
                             bf16* Msq2o /*b2*/, bf16* Msq1o /*b3*/,
                             bf16* Hoff2o /*b4*/) {
    const size_t MATE = (size_t)ND * ND;
    const size_t nper = MATE / 8;
    size_t g = (size_t)blockIdx.x * 256 + threadIdx.x;
    const bool c1 = (g >= nper);
    if (c1) g -= nper;
    const size_t i8 = g * 8;
    const float* s0 = S + (c1 ? 2 * MATE : 0) + i8;
    float p0[8], p1[8];
    loadS8(s0, p0); loadS8(s0 + MATE, p1);
    const short8 mv = *(const short8*)((const short*)(c1 ? M1io : M2io) + i8);
    short8 msq, hf, ht;
#pragma unroll
    for (int j = 0; j < 8; ++j) {
        const short qb = TOBF(-(p0[j] + p1[j]));
        msq[j] = qb;
        const float q = BF(qb);
        const float m = BF(mv[j]);
        hf[j] = TOBF(2.f * m + q);
        ht[j] = TOBF(q - 2.f * m);
    }
    if (c1) {
        *(short8*)((short*)Msq1o + i8) = msq;
        *(short8*)((short*)M1io + i8) = hf;
    } else {
        *(short8*)((short*)Msq2o + i8) = msq;
        *(short8*)((short*)Hoff2o + i8) = hf;
        *(short8*)((short*)M2io + i8) = ht;
    }
}

// red2: Goff = (s0+s1) + Msq  (in place over the Msq buffers)
__global__ void red_goff(const float* __restrict__ S, bf16* g2io /*b2*/, bf16* g1io /*b3*/) {
    const size_t MATE = (size_t)ND * ND;
    const size_t nper = MATE / 8;
    size_t g = (size_t)blockIdx.x * 256 + threadIdx.x;
    const bool c1 = (g >= nper);
    if (c1) g -= nper;
    const size_t i8 = g * 8;
    const float* s0 = S + (c1 ? 2 * MATE : 0) + i8;
    float p0[8], p1[8];
    loadS8(s0, p0); loadS8(s0 + MATE, p1);
    const short8 av = *(const short8*)((const short*)(c1 ? g1io : g2io) + i8);
    short8 o;
#pragma unroll
    for (int j = 0; j < 8; ++j)
        o[j] = TOBF((p0[j] + p1[j]) + BF(av[j]));
    *(short8*)((short*)(c1 ? g1io : g2io) + i8) = o;
}

// red3: P2T = s + I + Goff2 + HT2 -> b0 ; P1R = (s + I + Goff1 + Hoff1) @ R -> b1
__global__ void red_p(const float* __restrict__ S,
                      bf16* p2t /*b0: HT2 in, P2T out*/, const bf16* goff2 /*b2*/,
                      bf16* p1r /*b1: Hoff1 in, P1R out*/, const bf16* goff1 /*b3*/,
                      const float* __restrict__ thetaP) {
    const size_t MATE = (size_t)ND * ND;
    const size_t nper = MATE / 8;
    size_t g = (size_t)blockIdx.x * 256 + threadIdx.x;
    const bool c1 = (g >= nper);
    if (c1) g -= nper;
    const size_t i8 = g * 8;
    const float* s0 = S + (c1 ? 2 * MATE : 0) + i8;
    float p0[8], p1[8];
    loadS8(s0, p0); loadS8(s0 + MATE, p1);
    const short8 a1v = *(const short8*)((const short*)(c1 ? goff1 : goff2) + i8);
    const short8 a2v = *(const short8*)((const short*)(c1 ? p1r : p2t) + i8);
    float v[8];
#pragma unroll
    for (int j = 0; j < 8; ++j) {
        const size_t e = i8 + j;
        const float diag = ((e >> 11) == (e & (ND - 1))) ? 1.f : 0.f;
        v[j] = p0[j] + p1[j];
        v[j] += diag + BF(a1v[j]) + BF(a2v[j]);
    }
    short8 o;
    if (c1) {
        const float th = *thetaP;
        const float ct = cosf(th), st = sinf(th);
#pragma unroll
        for (int j = 0; j < 8; j += 2) {
            const float a = v[j], b = v[j + 1];
            o[j]     = TOBF(ct * a - st * b);
            o[j + 1] = TOBF(st * a + ct * b);
        }
        *(short8*)((short*)p1r + i8) = o;
    } else {
#pragma unroll
        for (int j = 0; j < 8; ++j) o[j] = TOBF(v[j]);
        *(short8*)((short*)p2t + i8) = o;
    }
}

// red4: QT = s0+s1+s2+s3 -> bf16
__global__ void red_qt(const float* __restrict__ S, bf16* __restrict__ q) {
    const size_t MATE = (size_t)ND * ND;
    const size_t i8 = ((size_t)blockIdx.x * 256 + threadIdx.x) * 8;
    float p0[8], p1[8], p2[8], p3[8];
    loadS8(S + i8, p0); loadS8(S + MATE + i8, p1);
    loadS8(S + 2 * MATE + i8, p2); loadS8(S + 3 * MATE + i8, p3);
    short8 o;
#pragma unroll
    for (int j = 0; j < 8; ++j)
        o[j] = TOBF(((p0[j] + p1[j]) + p2[j]) + p3[j]);
    *(short8*)((short*)q + i8) = o;
}

// ---------------- epilogue modes ----------------
enum { EPI_PLAIN = 0, EPI_NEG = 1, EPI_ADD1 = 2, EPI_P = 3, EPI_P_ROT = 4 };

// ---------------- 128x128 m97-structure GEMM core (fallback paths) -----------
template <int EPI, bool OF32>
__device__ __forceinline__ void gemm_core(
    short* aT, short* bT,
    const bf16* __restrict__ A, const bf16* __restrict__ Bt, void* __restrict__ Cp,
    const int Nc, const int K, const int bx, const int by,
    const bf16* __restrict__ add1, const bf16* __restrict__ add2,
    const float* __restrict__ thetaP)
{
    const int tid = threadIdx.x;
    const int lane = tid & 63;
    const int quad = lane >> 4;
    const int l15 = lane & 15;
    const int wv = tid >> 6;
    const int wr = (wv >> 1) << 6;
    const int wc = (wv & 1) << 6;

    const short* Ag = (const short*)A + (size_t)(by << 7) * K;
    const short* Bg = (const short*)Bt + (size_t)(bx << 7) * K;

    floatx4 acc[4][4];
#pragma unroll
    for (int i = 0; i < 4; ++i)
#pragma unroll
        for (int j = 0; j < 4; ++j)
            acc[i][j] = (floatx4){0.f, 0.f, 0.f, 0.f};

    for (int k0 = 0; k0 < K; k0 += 32) {
#pragma unroll
        for (int c = 0; c < 2; ++c) {
            const int ch = (c << 8) + (wv << 6) + lane;
            const int row = ch >> 2;
            const int kp = (ch & 3) << 3;
            const int ldsBase = ((c << 8) + (wv << 6)) << 3;
            gl2lds16(Ag + (size_t)row * K + k0 + kp, aT + ldsBase);
            gl2lds16(Bg + (size_t)row * K + k0 + kp, bT + ldsBase);
        }
        __syncthreads();
        short8 af[4], bfr[4];
#pragma unroll
        for (int mi = 0; mi < 4; ++mi)
            af[mi] = *(const short8*)(aT + ((wr + (mi << 4) + l15) << 5) + (quad << 3));
#pragma unroll
        for (int ni = 0; ni < 4; ++ni)
            bfr[ni] = *(const short8*)(bT + ((wc + (ni << 4) + l15) << 5) + (quad << 3));
#pragma unroll
        for (int mi = 0; mi < 4; ++mi)
#pragma unroll
            for (int ni = 0; ni < 4; ++ni)
                acc[mi][ni] = __builtin_amdgcn_mfma_f32_16x16x32_bf16(af[mi], bfr[ni], acc[mi][ni], 0, 0, 0);
        __syncthreads();
    }

    float ct = 0.f, st = 0.f;
    if (EPI == EPI_P_ROT) {
        const float th = *thetaP;
        ct = cosf(th);
        st = sinf(th);
    }

#pragma unroll
    for (int mi = 0; mi < 4; ++mi) {
#pragma unroll
        for (int ni = 0; ni < 4; ++ni) {
#pragma unroll
            for (int r = 0; r < 4; ++r) {
                const int row = (by << 7) + wr + (mi << 4) + (quad << 2) + r;
                const int col = (bx << 7) + wc + (ni << 4) + l15;
                const size_t idx = (size_t)row * Nc + col;
                float v = acc[mi][ni][r];
                if (EPI == EPI_NEG) v = -v;
                if (EPI == EPI_ADD1) v += __bfloat162float(add1[idx]);
                if (EPI == EPI_P)
                    v += (row == col ? 1.f : 0.f)
                       + __bfloat162float(add1[idx]) + __bfloat162float(add2[idx]);
                if (EPI == EPI_P_ROT) {
                    v += (row == col ? 1.f : 0.f)
                       + __bfloat162float(add1[idx]) + __bfloat162float(add2[idx]);
                    const float w = __shfl_xor(v, 1, 64);
                    v = (l15 & 1) ? (st * w + ct * v) : (ct * v - st * w);
                }
                if (OF32) ((float*)Cp)[idx] = v;
                else      ((bf16*)Cp)[idx] = __float2bfloat16(v);
            }
        }
    }
}

template <int EPI, bool OF32>
__launch_bounds__(256, 2) __global__
void gemm_one(const bf16* __restrict__ A, const bf16* __restrict__ Bt,
              void* __restrict__ Cp, const int Nc, const int K,
              const bf16* __restrict__ add1, const bf16* __restrict__ add2,
              const float* __restrict__ thetaP)
{
    __shared__ __attribute__((aligned(16))) short aT[128 * 32];
    __shared__ __attribute__((aligned(16))) short bT[128 * 32];
    const int nblk = Nc >> 7;
    const int b = xcd_swz(blockIdx.x, gridDim.x);
    gemm_core<EPI, OF32>(aT, bT, A, Bt, Cp, Nc, K, b % nblk, b / nblk,
                         add1, add2, thetaP);
}

template <int EPI0, int EPI1>
__launch_bounds__(256, 2) __global__
void gemm_dual(const bf16* A0, const bf16* B0, bf16* C0, const bf16* a10, const bf16* a20,
               const bf16* A1, const bf16* B1, bf16* C1, const bf16* a11, const bf16* a21,
               const float* thetaP)
{
    __shared__ __attribute__((aligned(16))) short aT[128 * 32];
    __shared__ __attribute__((aligned(16))) short bT[128 * 32];
    const int nblk = ND >> 7;          // 16
    const int nsub = nblk * nblk;      // 256
    int b = xcd_swz(blockIdx.x, gridDim.x);
    if (b < nsub) {
        gemm_core<EPI0, false>(aT, bT, A0, B0, (void*)C0, ND, ND, b % nblk, b / nblk, a10, a20, thetaP);
    } else {
        b -= nsub;
        gemm_core<EPI1, false>(aT, bT, A1, B1, (void*)C1, ND, ND, b % nblk, b / nblk, a11, a21, thetaP);
    }
}

// ================== 256x256 / BK=64 / 8-phase / counted-vmcnt core ===========
// (R3-proven schedule; generalized with kOff for split-K use.)

__device__ __forceinline__ void stage512(short* ldsT, const short* gT, const int K,
                                         const int kb, const int c0,
                                         const int wv, const int lane) {
    const int ch = c0 + (wv << 6) + lane;      // chunk index in 256x64 tile
    const int rw = ch >> 3;                    // row (8 chunks of 16B per row)
    const int cs = (ch & 7) ^ (rw & 7);        // inverse-swizzled source k-chunk
    gl2lds16(gT + (size_t)rw * K + kb + (cs << 3),
             ldsT + ((c0 + (wv << 6)) << 3));  // wave-uniform linear LDS dest
}

__device__ __forceinline__ void phase_mid() {
    __builtin_amdgcn_sched_barrier(0);
    __builtin_amdgcn_s_barrier();
    asm volatile("s_waitcnt lgkmcnt(0)" ::: "memory");
    __builtin_amdgcn_sched_barrier(0);
    __builtin_amdgcn_s_setprio(1);
}
__device__ __forceinline__ void phase_end() {
    __builtin_amdgcn_s_setprio(0);
    __builtin_amdgcn_sched_barrier(0);
    __builtin_amdgcn_s_barrier();
}

#define MFMA_BF16 __builtin_amdgcn_mfma_f32_16x16x32_bf16

__device__ __forceinline__ void tile256(
    short* Ac, short* Bc, short* An,
    const short* Ag, const short* Bg, const int K, const int nt, const int t,
    const int kOff,
    const int wv, const int lane, const int aBase, const int bBase,
    const int cOff0, const int cOff1, floatx4 (&acc)[8][4])
{
    short8 af[4][2], bb[4][2];
    const int kb1 = kOff + ((t + 1) << 6);
    const int kb2 = kOff + ((t + 2) << 6);

    // ---- phase 1: ds_read A rows mi0-3 + B ni0-1 (12 reads); stage (t+1) A2 -> An
#pragma unroll
    for (int ml = 0; ml < 4; ++ml) {
        af[ml][0] = *(const short8*)(Ac + aBase + (ml << 10) + cOff0);
        af[ml][1] = *(const short8*)(Ac + aBase + (ml << 10) + cOff1);
    }
#pragma unroll
    for (int ni = 0; ni < 2; ++ni) {
        bb[ni][0] = *(const short8*)(Bc + bBase + (ni << 10) + cOff0);
        bb[ni][1] = *(const short8*)(Bc + bBase + (ni << 10) + cOff1);
    }
    if (t + 1 < nt) { stage512(An, Ag, K, kb1, 512, wv, lane); stage512(An, Ag, K, kb1, 1536, wv, lane); }
    __builtin_amdgcn_sched_barrier(0);
    asm volatile("s_waitcnt lgkmcnt(8)" ::: "memory");
    phase_mid();
#pragma unroll
    for (int ml = 0; ml < 4; ++ml)
#pragma unroll
        for (int ni = 0; ni < 2; ++ni) {
            acc[ml][ni] = MFMA_BF16(af[ml][0], bb[ni][0], acc[ml][ni], 0, 0, 0);
            acc[ml][ni] = MFMA_BF16(af[ml][1], bb[ni][1], acc[ml][ni], 0, 0, 0);
        }
    phase_end();

    // ---- phase 2: ds_read B ni2-3 ; stage (t+2) A1 -> Ac
#pragma unroll
    for (int ni = 2; ni < 4; ++ni) {
        bb[ni][0] = *(const short8*)(Bc + bBase + (ni << 10) + cOff0);
        bb[ni][1] = *(const short8*)(Bc + bBase + (ni << 10) + cOff1);
    }
    if (t + 2 < nt) { stage512(Ac, Ag, K, kb2, 0, wv, lane); stage512(Ac, Ag, K, kb2, 1024, wv, lane); }
    phase_mid();
#pragma unroll
    for (int ml = 0; ml < 4; ++ml)
#pragma unroll
        for (int ni = 2; ni < 4; ++ni) {
            acc[ml][ni] = MFMA_BF16(af[ml][0], bb[ni][0], acc[ml][ni], 0, 0, 0);
            acc[ml][ni] = MFMA_BF16(af[ml][1], bb[ni][1], acc[ml][ni], 0, 0, 0);
        }
    phase_end();

    // ---- phase 3: ds_read A rows mi4-7 ; stage (t+2) B rows 0-127
#pragma unroll
    for (int ml = 0; ml < 4; ++ml) {
        af[ml][0] = *(const short8*)(Ac + aBase + 4096 + (ml << 10) + cOff0);
        af[ml][1] = *(const short8*)(Ac + aBase + 4096 + (ml << 10) + cOff1);
    }
    if (t + 2 < nt) { stage512(Bc, Bg, K, kb2, 0, wv, lane); stage512(Bc, Bg, K, kb2, 512, wv, lane); }
    phase_mid();
#pragma unroll
    for (int ml = 0; ml < 4; ++ml)
#pragma unroll
        for (int ni = 0; ni < 2; ++ni) {
            acc[4 + ml][ni] = MFMA_BF16(af[ml][0], bb[ni][0], acc[4 + ml][ni], 0, 0, 0);
            acc[4 + ml][ni] = MFMA_BF16(af[ml][1], bb[ni][1], acc[4 + ml][ni], 0, 0, 0);
        }
    phase_end();

    // ---- phase 4: stage (t+2) B rows 128-255 ; counted vmcnt for tile t+1
    if (t + 2 < nt) { stage512(Bc, Bg, K, kb2, 1024, wv, lane); stage512(Bc, Bg, K, kb2, 1536, wv, lane); }
    __builtin_amdgcn_sched_barrier(0);
    if (t < nt - 2) asm volatile("s_waitcnt vmcnt(6)" ::: "memory");
    else            asm volatile("s_waitcnt vmcnt(0)" ::: "memory");
    __builtin_amdgcn_s_barrier();
    __builtin_amdgcn_sched_barrier(0);
    __builtin_amdgcn_s_setprio(1);
#pragma unroll
    for (int ml = 0; ml < 4; ++ml)
#pragma unroll
        for (int ni = 2; ni < 4; ++ni) {
            acc[4 + ml][ni] = MFMA_BF16(af[ml][0], bb[ni][0], acc[4 + ml][ni], 0, 0, 0);
            acc[4 + ml][ni] = MFMA_BF16(af[ml][1], bb[ni][1], acc[4 + ml][ni], 0, 0, 0);
        }
    phase_end();
}

__launch_bounds__(512, 2) __global__
void gemm_big256(const bf16* __restrict__ A, const bf16* __restrict__ Bt,
                 float* __restrict__ C, const int Nc, const int K)
{
    __shared__ __attribute__((aligned(16))) short smem[65536];   // 128 KiB
    short* A0s = smem;
    short* A1s = smem + 16384;
    short* B0s = smem + 32768;
    short* B1s = smem + 49152;

    const int nblkx = Nc >> 8;                 // 8
    const int b = xcd_swz(blockIdx.x, gridDim.x);
    const int bx = b % nblkx;
    const int by = b / nblkx;
    const int tid = threadIdx.x;
    const int lane = tid & 63;
    const int q = lane >> 4;
    const int l15 = lane & 15;
    const int wv = tid >> 6;
    const int wm = wv >> 2;
    const int wn = wv & 3;

    const short* Ag = (const short*)A + (size_t)(by << 8) * K;
    const short* Bg = (const short*)Bt + (size_t)(bx << 8) * K;

    const int swz = l15 & 7;
    const int aBase = ((wm << 7) + l15) << 6;
    const int bBase = ((wn << 6) + l15) << 6;
    const int cOff0 = (q ^ swz) << 3;
    const int cOff1 = ((q + 4) ^ swz) << 3;

    floatx4 acc[8][4];
#pragma unroll
    for (int i = 0; i < 8; ++i)
#pragma unroll
        for (int j = 0; j < 4; ++j)
            acc[i][j] = (floatx4){0.f, 0.f, 0.f, 0.f};

    const int nt = K >> 6;

    stage512(A0s, Ag, K, 0, 0,    wv, lane);
    stage512(A0s, Ag, K, 0, 512,  wv, lane);
    stage512(A0s, Ag, K, 0, 1024, wv, lane);
    stage512(A0s, Ag, K, 0, 1536, wv, lane);
    stage512(B0s, Bg, K, 0, 0,    wv, lane);
    stage512(B0s, Bg, K, 0, 512,  wv, lane);
    stage512(B0s, Bg, K, 0, 1024, wv, lane);
    stage512(B0s, Bg, K, 0, 1536, wv, lane);
    stage512(A1s, Ag, K, 64, 0,    wv, lane);
    stage512(A1s, Ag, K, 64, 1024, wv, lane);
    stage512(B1s, Bg, K, 64, 0,    wv, lane);
    stage512(B1s, Bg, K, 64, 512,  wv, lane);
    stage512(B1s, Bg, K, 64, 1024, wv, lane);
    stage512(B1s, Bg, K, 64, 1536, wv, lane);
    __builtin_amdgcn_sched_barrier(0);
    asm volatile("s_waitcnt vmcnt(6)" ::: "memory");
    __builtin_amdgcn_s_barrier();

    for (int t = 0; t < nt; t += 2) {
        tile256(A0s, B0s, A1s, Ag, Bg, K, nt, t,     0, wv, lane, aBase, bBase, cOff0, cOff1, acc);
        tile256(A1s, B1s, A0s, Ag, Bg, K, nt, t + 1, 0, wv, lane, aBase, bBase, cOff0, cOff1, acc);
    }

#pragma unroll
    for (int mi = 0; mi < 8; ++mi)
#pragma unroll
        for (int ni = 0; ni < 4; ++ni)
#pragma unroll
            for (int r = 0; r < 4; ++r) {
                const int row = (by << 8) + (wm << 7) + (mi << 4) + (q << 2) + r;
                const int col = (bx << 8) + (wn << 6) + (ni << 4) + l15;
                C[(size_t)row * Nc + col] = acc[mi][ni][r];
            }
}

// ---------------- split-K chain GEMM: 256 blocks, fp32 partials to S ---------
// NT=16: 2 GEMMs x 2 K-splits (K=1024 each).  NT=8: 1 GEMM x 4 K-splits (512).
// Output sub i -> S + i*ND*ND (row-major fp32 2048^2 partial).
template <int NT>
__launch_bounds__(512, 2) __global__
void gemm_sk(const bf16* __restrict__ A0, const bf16* __restrict__ B0,
             const bf16* __restrict__ A1, const bf16* __restrict__ B1,
             float* __restrict__ S)
{
    __shared__ __attribute__((aligned(16))) short smem[65536];   // 128 KiB
    short* A0s = smem;
    short* A1s = smem + 16384;
    short* B0s = smem + 32768;
    short* B1s = smem + 49152;

    const int b = xcd_swz(blockIdx.x, gridDim.x);   // grid = 256
    const int sub = b >> 6;
    const int t6 = b & 63;
    const int bx = t6 & 7;
    const int by = t6 >> 3;
    const bf16* A; const bf16* Bt; int kOff;
    if (NT == 16) { A = (sub & 2) ? A1 : A0; Bt = (sub & 2) ? B1 : B0; kOff = (sub & 1) << 10; }
    else          { A = A0; Bt = B0; kOff = sub << 9; }
    float* C = S + (size_t)sub * ((size_t)ND * ND);
    const int K = ND;

    const int tid = threadIdx.x;
    const int lane = tid & 63;
    const int q = lane >> 4;
    const int l15 = lane & 15;
    const int wv = tid >> 6;
    const int wm = wv >> 2;
    const int wn = wv & 3;

    const short* Ag = (const short*)A + (size_t)(by << 8) * K;
    const short* Bg = (const short*)Bt + (size_t)(bx << 8) * K;

    const int swz = l15 & 7;
    const int aBase = ((wm << 7) + l15) << 6;
    const int bBase = ((wn << 6) + l15) << 6;
    const int cOff0 = (q ^ swz) << 3;
    const int cOff1 = ((q + 4) ^ swz) << 3;

    floatx4 acc[8][4];
#pragma unroll
    for (int i = 0; i < 8; ++i)
#pragma unroll
        for (int j = 0; j < 4; ++j)
            acc[i][j] = (floatx4){0.f, 0.f, 0.f, 0.f};

    // prologue: T0 full + T1 {A-part1, B-full}; wait T0.
    stage512(A0s, Ag, K, kOff, 0,    wv, lane);
    stage512(A0s, Ag, K, kOff, 512,  wv, lane);
    stage512(A0s, Ag, K, kOff, 1024, wv, lane);
    stage512(A0s, Ag, K, kOff, 1536, wv, lane);
    stage512(B0s, Bg, K, kOff, 0,    wv, lane);
    stage512(B0s, Bg, K, kOff, 512,  wv, lane);
    stage512(B0s, Bg, K, kOff, 1024, wv, lane);
    stage512(B0s, Bg, K, kOff, 1536, wv, lane);
    stage512(A1s, Ag, K, kOff + 64, 0,    wv, lane);
    stage512(A1s, Ag, K, kOff + 64, 1024, wv, lane);
    stage512(B1s, Bg, K, kOff + 64, 0,    wv, lane);
    stage512(B1s, Bg, K, kOff + 64, 512,  wv, lane);
    stage512(B1s, Bg, K, kOff + 64, 1024, wv, lane);
    stage512(B1s, Bg, K, kOff + 64, 1536, wv, lane);
    __builtin_amdgcn_sched_barrier(0);
    asm volatile("s_waitcnt vmcnt(6)" ::: "memory");
    __builtin_amdgcn_s_barrier();

    for (int t = 0; t < NT; t += 2) {
        tile256(A0s, B0s, A1s, Ag, Bg, K, NT, t,     kOff, wv, lane, aBase, bBase, cOff0, cOff1, acc);
        tile256(A1s, B1s, A0s, Ag, Bg, K, NT, t + 1, kOff, wv, lane, aBase, bBase, cOff0, cOff1, acc);
    }

#pragma unroll
    for (int mi = 0; mi < 8; ++mi)
#pragma unroll
        for (int ni = 0; ni < 4; ++ni)
#pragma unroll
            for (int r = 0; r < 4; ++r) {
                const int row = (by << 8) + (wm << 7) + (mi << 4) + (q << 2) + r;
                const int col = (bx << 8) + (wn << 6) + (ni << 4) + l15;
                C[(size_t)row * ND + col] = acc[mi][ni][r];
            }
}

// ---------------- Tier-B (round-2 proven) manual-staging GEMM ----------------
template <int EPI, bool AF32, bool OF32>
__launch_bounds__(256, 2) __global__
void gemm_bt(const void* __restrict__ Ap, const bf16* __restrict__ Bt,
             void* __restrict__ Cp, const int Nc, const int K,
             const bf16* __restrict__ add1, const bf16* __restrict__ add2,
             const float* __restrict__ thetaP)
{
    __shared__ __attribute__((aligned(16))) short aT[128 * 32];
    __shared__ __attribute__((aligned(16))) short bT[128 * 32];

    const int nblk = Nc >> 7;
    const int bx = blockIdx.x % nblk;
    const int by = blockIdx.x / nblk;
    const int tid = threadIdx.x;
    const int lane = tid & 63;
    const int quad = lane >> 4;
    const int l15 = lane & 15;
    const int wv = tid >> 6;
    const int wr = (wv >> 1) << 6;
    const int wc = (wv & 1) << 6;

    const short* Ag = (const short*)Ap + (size_t)(by << 7) * K;
    const float* Agf = (const float*)Ap + (size_t)(by << 7) * K;
    const short* Bg = (const short*)Bt + (size_t)(bx << 7) * K;

    floatx4 acc[4][4];
#pragma unroll
    for (int i = 0; i < 4; ++i)
#pragma unroll
        for (int j = 0; j < 4; ++j)
            acc[i][j] = (floatx4){0.f, 0.f, 0.f, 0.f};

    for (int k0 = 0; k0 < K; k0 += 32) {
#pragma unroll
        for (int c = 0; c < 2; ++c) {
            const int ch = tid + (c << 8);
            const int row = ch >> 2;
            const int kp = (ch & 3) << 3;
            if (AF32) {
                const float4 f0 = *(const float4*)(Agf + (size_t)row * K + k0 + kp);
                const float4 f1 = *(const float4*)(Agf + (size_t)row * K + k0 + kp + 4);
                short8 pk;
                pk[0] = __builtin_bit_cast(short, __float2bfloat16(f0.x));
                pk[1] = __builtin_bit_cast(short, __float2bfloat16(f0.y));
                pk[2] = __builtin_bit_cast(short, __float2bfloat16(f0.z));
                pk[3] = __builtin_bit_cast(short, __float2bfloat16(f0.w));
                pk[4] = __builtin_bit_cast(short, __float2bfloat16(f1.x));
                pk[5] = __builtin_bit_cast(short, __float2bfloat16(f1.y));
                pk[6] = __builtin_bit_cast(short, __float2bfloat16(f1.z));
                pk[7] = __builtin_bit_cast(short, __float2bfloat16(f1.w));
                *(short8*)(aT + (row << 5) + kp) = pk;
            } else {
                *(int4*)(aT + (row << 5) + kp) = *(const int4*)(Ag + (size_t)row * K + k0 + kp);
            }
            *(int4*)(bT + (row << 5) + kp) = *(const int4*)(Bg + (size_t)row * K + k0 + kp);
        }
        __syncthreads();
        short8 af[4], bfr[4];
#pragma unroll
        for (int mi = 0; mi < 4; ++mi)
            af[mi] = *(const short8*)(aT + ((wr + (mi << 4) + l15) << 5) + (quad << 3));
#pragma unroll
        for (int ni = 0; ni < 4; ++ni)
            bfr[ni] = *(const short8*)(bT + ((wc + (ni << 4) + l15) << 5) + (quad << 3));
#pragma unroll
        for (int mi = 0; mi < 4; ++mi)
#pragma unroll
            for (int ni = 0; ni < 4; ++ni)
                acc[mi][ni] = __builtin_amdgcn_mfma_f32_16x16x32_bf16(af[mi], bfr[ni], acc[mi][ni], 0, 0, 0);
        __syncthreads();
    }

    float ct = 0.f, st = 0.f;
    if (EPI == EPI_P_ROT) {
        const float th = *thetaP;
        ct = cosf(th);
        st = sinf(th);
    }

#pragma unroll
    for (int mi = 0; mi < 4; ++mi) {
#pragma unroll
        for (int ni = 0; ni < 4; ++ni) {
#pragma unroll
            for (int r = 0; r < 4; ++r) {
                const int row = (by << 7) + wr + (mi << 4) + (quad << 2) + r;
                const int col = (bx << 7) + wc + (ni << 4) + l15;
                const size_t idx = (size_t)row * Nc + col;
                float v = acc[mi][ni][r];
                if (EPI == EPI_NEG) v = -v;
                if (EPI == EPI_ADD1) v += __bfloat162float(add1[idx]);
                if (EPI == EPI_P || EPI == EPI_P_ROT)
                    v += (row == col ? 1.f : 0.f)
                       + __bfloat162float(add1[idx]) + __bfloat162float(add2[idx]);
                if (EPI == EPI_P_ROT) {
                    const float w = __shfl_xor(v, 1, 64);
                    v = (l15 & 1) ? (st * w + ct * v) : (ct * v - st * w);
                }
                if (OF32) ((float*)Cp)[idx] = v;
                else      ((bf16*)Cp)[idx] = __float2bfloat16(v);
            }
        }
    }
}

// ---------------- launch ----------------
// out = x @ P1 @ R @ P2,  P = (I+M)^2 (I+M^2+M^4),  M = 0.5(W^T - W)
// Tier A+ (tokens%256==0 and tokens*ND >= 8*ND^2, i.e. d_out holds 8 fp32
//   2048^2 partials by construction): entire chain on the 256^2 8-phase kernel
//   via split-K, fp32 partials in d_out, vectorized deterministic reduces.
//   NOTE R5 bug: the old gate compared out_size (ELEMENTS) against BYTES and
//   never fired; gate now derived from tokens only.
// Tier A fallback: R4 dual-chain (with big256 final when tokens%256==0).
// Tier B: round-2 proven sequence.

extern "C" void kernel_launch(void* const* d_in, const int* in_sizes, int n_in,
                              void* d_out, int out_size, void* d_ws, size_t ws_size,
                              hipStream_t stream)
{
    const float* x = (const float*)d_in[0];
    const float* u1 = (const float*)d_in[1];
    const float* u2 = (const float*)d_in[2];
    const float* th = (const float*)d_in[3];
    float* out = (float*)d_out;
    const int tokens = in_sizes[0] / ND;

    const size_t MAT = (size_t)ND * ND;
    const size_t XBE = (size_t)tokens * ND;

    const dim3 blk(256);
    const int gSkew = (ND / 32) * (ND / 32);
    const int gElem = (int)(MAT / 256);
    const int gSm = (ND / 128) * (ND / 128);        // 256
    const int gBig = (tokens / 128) * (ND / 128);

    if (ws_size >= (6 * MAT + XBE) * sizeof(bf16)) {
        bf16* base = (bf16*)d_ws;
        bf16* b0 = base;            // M2 -> HT2 -> P2T
        bf16* b1 = base + MAT;      // M1 -> Hoff1 -> P1R
        bf16* b2 = base + 2 * MAT;  // Msq2 -> Goff2 -> QT
        bf16* b3 = base + 3 * MAT;  // Msq1 -> Goff1
        bf16* b4 = base + 4 * MAT;  // Hoff2
        bf16* xb = base + 6 * MAT;  // x as bf16

        convert_f32_bf16<<<(int)(XBE / 2048), blk, 0, stream>>>(x, xb);
        build_skew2<<<2 * gSkew, blk, 0, stream>>>(u2, b0, u1, b1);

        if ((tokens & 255) == 0 && XBE >= 8 * MAT) {
            // ---------------- Tier A+: split-K chain, partials in d_out ------
            float* S = out;
            const int gRed = (int)(2 * MAT / 2048);
            // stage1: Msq partials  (g0 = M2@M2^T, g1 = M1@M1^T)
            gemm_sk<16><<<256, dim3(512), 0, stream>>>(b0, b0, b1, b1, S);
            // Msq = -(s0+s1); Hoff = 2M+Msq; HT2 = Msq2-2M2 (fused)
            red_msq_hoff<<<gRed, blk, 0, stream>>>(S, b0, b1, b2, b3, b4);
            // stage2: Goff partials (g0 = Msq2@Msq2, g1 = Msq1@Msq1)
            gemm_sk<16><<<256, dim3(512), 0, stream>>>(b2, b2, b3, b3, S);
            // Goff = (s0+s1) + Msq  (in place over Msq)
            red_goff<<<gRed, blk, 0, stream>>>(S, b2, b3);
            // stage3: P partials (g0 = Goff2@Hoff2^T, g1 = Hoff1@Goff1^T)
            gemm_sk<16><<<256, dim3(512), 0, stream>>>(b2, b4, b1, b3, S);
            // P2T = s+I+Goff2+HT2 -> b0 ; P1R = (s+I+Goff1+Hoff1)@R -> b1
            red_p<<<gRed, blk, 0, stream>>>(S, b0, b2, b1, b3, th);
            // QT partials: P2T @ P1R^T, split-K=4
            gemm_sk<8><<<256, dim3(512), 0, stream>>>(b0, b1, nullptr, nullptr, S);
            red_qt<<<(int)(MAT / 2048), blk, 0, stream>>>(S, b2);
            // out = x @ QT^T
            const int gBig256 = (tokens >> 8) * (ND >> 8);   // 512
            gemm_big256<<<gBig256, dim3(512), 0, stream>>>(xb, b2, out, ND, ND);
        } else {
            // ---------------- Tier A fallback (R4 path) ----------------------
            bf16* b5 = base + 5 * MAT;
            gemm_dual<EPI_NEG, EPI_NEG><<<2 * gSm, blk, 0, stream>>>(
                b0, b0, b2, nullptr, nullptr,  b1, b1, b3, nullptr, nullptr, nullptr);
            gemm_dual<EPI_ADD1, EPI_ADD1><<<2 * gSm, blk, 0, stream>>>(
                b2, b2, b4, b2, nullptr,  b3, b3, b5, b3, nullptr, nullptr);
            build_hoffs<<<(int)(2 * MAT / 2048), blk, 0, stream>>>(b0, b2, b2, b0, b1, b3, b3);
            gemm_dual<EPI_P, EPI_P_ROT><<<2 * gSm, blk, 0, stream>>>(
                b4, b2, b0, b4, b0,  b3, b5, b1, b5, b3, th);
            gemm_one<EPI_PLAIN, false><<<gSm, blk, 0, stream>>>(b0, b1, b2, ND, ND, nullptr, nullptr, nullptr);
            if ((tokens & 255) == 0) {
                const int gBig256 = (tokens >> 8) * (ND >> 8);
                gemm_big256<<<gBig256, dim3(512), 0, stream>>>(xb, b2, out, ND, ND);
            } else {
                gemm_one<EPI_PLAIN, true><<<gBig, blk, 0, stream>>>(xb, b2, out, ND, ND, nullptr, nullptr, nullptr);
            }
        }
    } else {
        // ---------------- Tier B (round-2 proven) ----------------
        bf16* A = (bf16*)d_ws;
        bf16* B = A + MAT;
        bf16* Cb = B + MAT;
        bf16* D = Cb + MAT;
        bf16* E = D + MAT;

        build_skew2<<<gSkew, blk, 0, stream>>>(u2, A, u2, A);
        gemm_bt<EPI_NEG, false, false><<<gSm, blk, 0, stream>>>(A, A, B, ND, ND, nullptr, nullptr, nullptr);
        gemm_bt<EPI_ADD1, false, false><<<gSm, blk, 0, stream>>>(B, B, Cb, ND, ND, B, nullptr, nullptr);
        build_hoff<<<gElem, blk, 0, stream>>>(A, B, D, E);
        gemm_bt<EPI_P, false, false><<<gSm, blk, 0, stream>>>(Cb, D, A, ND, ND, Cb, E, nullptr);

        build_skew2<<<gSkew, blk, 0, stream>>>(u1, B, u1, B);
        gemm_bt<EPI_NEG, false, false><<<gSm, blk, 0, stream>>>(B, B, Cb, ND, ND, nullptr, nullptr, nullptr);
        gemm_bt<EPI_ADD1, false, false><<<gSm, blk, 0, stream>>>(Cb, Cb, D, ND, ND, Cb, nullptr, nullptr);
        build_hoff<<<gElem, blk, 0, stream>>>(B, Cb, E, B);
        gemm_bt<EPI_P_ROT, false, false><<<gSm, blk, 0, stream>>>(E, D, Cb, ND, ND, D, E, th);

        gemm_bt<EPI_PLAIN, false, false><<<gSm, blk, 0, stream>>>(A, Cb, D, ND, ND, nullptr, nullptr, nullptr);
        gemm_bt<EPI_PLAIN, true, true><<<gBig, blk, 0, stream>>>(x, D, out, ND, ND, nullptr, nullptr, nullptr);
    }
}